// Round 4
// baseline (66.156 us; speedup 1.0000x reference)
//
#include <hip/hip_runtime.h>

// Problem constants (from reference setup_inputs):
//   logits: (N=4, C=19, H=512, W=1024) float32, target unused.
#define NCLS 19
#define NSMP 4
#define HW   (512 * 1024)
#define NVAL 57          // S1[19] | S2[19] | cnt[19] per block
#define PSTRIDE 64       // padded floats per block row in partials
#define NBLK 2048        // 512 blocks per sample

// Main kernel: 2048 blocks x 256 threads, 4 px/thread, 1024 px/block.
// Block b handles sample n = b/512. Per-block partial sums go to
// partials[b*64 + 0..56] via plain stores — NO global atomics (R3 post-mortem:
// 116K same-line atomic adds onto 8 cache lines serialize at L2 for ~29 us).
__global__ __launch_bounds__(256) void cl_main(const float* __restrict__ logits,
                                               float* __restrict__ partials) {
    __shared__ float sb[NVAL];   // [S1_19 | S2_19 | cnt_19]
    const int tid = threadIdx.x;
    if (tid < NVAL) sb[tid] = 0.0f;
    __syncthreads();

    const long long p   = ((long long)blockIdx.x * 256 + tid) * 4;  // pixel idx in N*HW
    const int       n   = (int)(p / HW);
    const long long off = p - (long long)n * HW;
    const float* base = logits + (size_t)n * NCLS * HW + off;

    // Batch all 19 channel loads (R2 structure, unchanged).
    float4 v[NCLS];
    #pragma unroll
    for (int c = 0; c < NCLS; ++c) {
        v[c] = *(const float4*)(base + (size_t)c * HW);
    }
    asm volatile("" ::: "memory");

    float s1[4], s2[4], mv[4];
    int   mi[4];
    {
        const float a0[4] = {v[0].x, v[0].y, v[0].z, v[0].w};
        #pragma unroll
        for (int j = 0; j < 4; ++j) {
            s1[j] = a0[j];
            s2[j] = a0[j] * a0[j];
            mv[j] = a0[j];
            mi[j] = 0;
        }
    }
    #pragma unroll
    for (int c = 1; c < NCLS; ++c) {
        const float a[4] = {v[c].x, v[c].y, v[c].z, v[c].w};
        #pragma unroll
        for (int j = 0; j < 4; ++j) {
            s1[j] += a[j];
            s2[j]  = fmaf(a[j], a[j], s2[j]);
            if (a[j] > mv[j]) { mv[j] = a[j]; mi[j] = c; }  // strict > = first-index argmax
        }
    }

    #pragma unroll
    for (int j = 0; j < 4; ++j) {
        atomicAdd(&sb[mi[j]],      s1[j]);
        atomicAdd(&sb[19 + mi[j]], s2[j]);
        atomicAdd(&sb[38 + mi[j]], 1.0f);
    }
    __syncthreads();

    if (tid < PSTRIDE) {
        partials[(size_t)blockIdx.x * PSTRIDE + tid] = (tid < NVAL) ? sb[tid] : 0.0f;
    }
}

// Final kernel: ONE block, 4 waves; wave w reduces the 512 partial rows of
// sample w (8 rows per lane), butterfly-reduces 60 accumulators, computes the
// 19 class norms, and writes the scalar loss. All register indices static.
__global__ __launch_bounds__(256) void cl_final(const float* __restrict__ partials,
                                                float* __restrict__ out) {
    const int tid  = threadIdx.x;
    const int w    = tid >> 6;    // wave index == sample n
    const int lane = tid & 63;

    float acc[60];
    #pragma unroll
    for (int i = 0; i < 60; ++i) acc[i] = 0.0f;

    #pragma unroll
    for (int k = 0; k < 8; ++k) {
        const float* row = partials + (size_t)(w * 512 + lane + (k << 6)) * PSTRIDE;
        #pragma unroll
        for (int vq = 0; vq < 15; ++vq) {
            float4 t = *(const float4*)(row + vq * 4);
            acc[4 * vq + 0] += t.x;
            acc[4 * vq + 1] += t.y;
            acc[4 * vq + 2] += t.z;
            acc[4 * vq + 3] += t.w;
        }
    }

    // Butterfly sum across the wave: every lane ends with the 57 segment sums.
    #pragma unroll
    for (int s = 1; s < 64; s <<= 1) {
        #pragma unroll
        for (int i = 0; i < 60; ++i) acc[i] += __shfl_xor(acc[i], s, 64);
    }

    float loss = 0.0f;
    if (lane < NCLS) {
        const float S1  = acc[lane];
        const float S2  = acc[19 + lane];
        const float cnt = acc[38 + lane];
        const float K   = fmaxf(cnt, 1.0f) * (float)NCLS;
        const float sq  = fmaxf(S2 - S1 * S1 / K, 0.0f);
        loss = (cnt > 0.0f) ? sqrtf(sq) : 0.0f;
    }
    // Sum the 19 per-class norms within the lower 32-lane group (lanes 19..31 are 0).
    #pragma unroll
    for (int s = 1; s < 32; s <<= 1) loss += __shfl_xor(loss, s, 64);

    __shared__ float L[4];
    if (lane == 0) L[w] = loss;
    __syncthreads();
    if (tid == 0) out[0] = (L[0] + L[1] + L[2] + L[3]) * 0.25f;
}

extern "C" void kernel_launch(void* const* d_in, const int* in_sizes, int n_in,
                              void* d_out, int out_size, void* d_ws, size_t ws_size,
                              hipStream_t stream) {
    const float* logits = (const float*)d_in[0];
    // d_in[1] (target) is unused by the reference computation.
    float* partials = (float*)d_ws;       // 2048 * 64 * 4 B = 512 KB
    float* out      = (float*)d_out;

    cl_main<<<NBLK, 256, 0, stream>>>(logits, partials);
    cl_final<<<1, 256, 0, stream>>>(partials, out);
}

// Round 5
// 57.856 us; speedup vs baseline: 1.1435x; 1.1435x over previous
//
#include <hip/hip_runtime.h>

// Problem constants: logits (N=4, C=19, H=512, W=1024) float32; target unused.
#define NCLS 19
#define NSMP 4
#define HW   (512 * 1024)
#define NSEG (NSMP * NCLS)   // 76 segments

// ws layout (floats): [0..76) = S1, [76..152) = S2, [152..228) = cnt
//
// Main: 2048 blocks x 512 threads, 2 px/thread (float2), 1024 px/block.
// Occupancy probe: __launch_bounds__(512, 8) forces VGPR<=64 -> 8 waves/SIMD
// (32 waves/CU, 2x R2) to test whether the ~3.3 TB/s effective read BW is
// wave-MLP-limited or a hard per-CU outstanding-read cap.
__global__ __launch_bounds__(512, 8) void cl_main(const float* __restrict__ logits,
                                                  float* __restrict__ ws) {
    __shared__ float sb[3 * NCLS];   // [S1_19 | S2_19 | cnt_19]
    const int tid = threadIdx.x;
    if (tid < 3 * NCLS) sb[tid] = 0.0f;
    __syncthreads();

    const int    n   = blockIdx.x >> 9;                     // 512 blocks per sample
    const size_t off = ((size_t)(blockIdx.x & 511)) * 1024 + (size_t)tid * 2;
    const float* base = logits + (size_t)n * NCLS * HW + off;

    // Batch all 19 channel loads (float2 each -> 38 data VGPRs).
    float2 v[NCLS];
    #pragma unroll
    for (int c = 0; c < NCLS; ++c) {
        v[c] = *(const float2*)(base + (size_t)c * HW);
    }
    asm volatile("" ::: "memory");

    float s1[2], s2[2], mv[2];
    int   mi[2];
    {
        const float a0[2] = {v[0].x, v[0].y};
        #pragma unroll
        for (int j = 0; j < 2; ++j) {
            s1[j] = a0[j];
            s2[j] = a0[j] * a0[j];
            mv[j] = a0[j];
            mi[j] = 0;
        }
    }
    #pragma unroll
    for (int c = 1; c < NCLS; ++c) {
        const float a[2] = {v[c].x, v[c].y};
        #pragma unroll
        for (int j = 0; j < 2; ++j) {
            s1[j] += a[j];
            s2[j]  = fmaf(a[j], a[j], s2[j]);
            if (a[j] > mv[j]) { mv[j] = a[j]; mi[j] = c; }  // strict > = first-index argmax
        }
    }

    #pragma unroll
    for (int j = 0; j < 2; ++j) {
        atomicAdd(&sb[mi[j]],      s1[j]);
        atomicAdd(&sb[19 + mi[j]], s2[j]);
        atomicAdd(&sb[38 + mi[j]], 1.0f);
    }
    __syncthreads();

    if (tid < NCLS) {
        const int seg = n * NCLS + tid;
        atomicAdd(&ws[seg],            sb[tid]);
        atomicAdd(&ws[NSEG + seg],     sb[19 + tid]);
        atomicAdd(&ws[2 * NSEG + seg], sb[38 + tid]);
    }
}

__global__ void cl_final(const float* __restrict__ ws, float* __restrict__ out) {
    __shared__ float red[128];
    const int i = threadIdx.x;
    float v = 0.0f;
    if (i < NSEG) {
        const float S1  = ws[i];
        const float S2  = ws[NSEG + i];
        const float cnt = ws[2 * NSEG + i];
        const float K   = fmaxf(cnt, 1.0f) * (float)NCLS;
        const float sq  = fmaxf(S2 - S1 * S1 / K, 0.0f);
        v = (cnt > 0.0f) ? sqrtf(sq) : 0.0f;
    }
    red[i] = v;
    __syncthreads();
    #pragma unroll
    for (int s = 64; s > 0; s >>= 1) {
        if (i < s) red[i] += red[i + s];
        __syncthreads();
    }
    if (i == 0) out[0] = red[0] / (float)NSMP;
}

extern "C" void kernel_launch(void* const* d_in, const int* in_sizes, int n_in,
                              void* d_out, int out_size, void* d_ws, size_t ws_size,
                              hipStream_t stream) {
    const float* logits = (const float*)d_in[0];
    // d_in[1] (target) is unused by the reference computation.
    float* ws  = (float*)d_ws;
    float* out = (float*)d_out;

    hipMemsetAsync(ws, 0, 3 * NSEG * sizeof(float), stream);
    cl_main<<<2048, 512, 0, stream>>>(logits, ws);
    cl_final<<<1, 128, 0, stream>>>(ws, out);
}